// Round 1
// baseline (153.073 us; speedup 1.0000x reference)
//
#include <hip/hip_runtime.h>
#include <math.h>

// ---------------------------------------------------------------------------
// Kernel 1: compute E_k = expm(t_k * (M + M0)) for each k (3x3 expm via
// scaling-and-squaring + 12-term Taylor/Horner). Writes E row-major (9 floats
// per k) into workspace. Tiny: one block, one thread per t.
// ---------------------------------------------------------------------------
__global__ void expm_kernel(const float* __restrict__ t,
                            const float* __restrict__ M,
                            const float* __restrict__ M0,
                            float* __restrict__ E_out,
                            int T) {
    int k = blockIdx.x * blockDim.x + threadIdx.x;
    if (k >= T) return;

    float tk = t[k];
    float B[9];
#pragma unroll
    for (int i = 0; i < 9; ++i) B[i] = tk * (M[i] + M0[i]);

    // infinity norm (max abs row sum)
    float norm = 0.f;
#pragma unroll
    for (int i = 0; i < 3; ++i) {
        float rs = fabsf(B[i * 3]) + fabsf(B[i * 3 + 1]) + fabsf(B[i * 3 + 2]);
        norm = fmaxf(norm, rs);
    }
    // scale so that ||B/2^s|| <= 0.25
    int s = 0;
    while (norm > 0.25f && s < 40) { norm *= 0.5f; ++s; }
    float scale = exp2f((float)(-s));
#pragma unroll
    for (int i = 0; i < 9; ++i) B[i] *= scale;

    // Taylor: E = sum_{k=0..12} B^k / k!
    float P[9], E[9];
#pragma unroll
    for (int i = 0; i < 9; ++i) { P[i] = (i % 4 == 0) ? 1.f : 0.f; E[i] = P[i]; }
    for (int n = 1; n <= 12; ++n) {
        float inv = 1.0f / (float)n;
        float Q[9];
#pragma unroll
        for (int i = 0; i < 3; ++i)
#pragma unroll
            for (int j = 0; j < 3; ++j)
                Q[i * 3 + j] = (P[i * 3 + 0] * B[0 * 3 + j] +
                                P[i * 3 + 1] * B[1 * 3 + j] +
                                P[i * 3 + 2] * B[2 * 3 + j]) * inv;
#pragma unroll
        for (int i = 0; i < 9; ++i) { P[i] = Q[i]; E[i] += Q[i]; }
    }
    // repeated squaring
    for (int q = 0; q < s; ++q) {
        float Q[9];
#pragma unroll
        for (int i = 0; i < 3; ++i)
#pragma unroll
            for (int j = 0; j < 3; ++j)
                Q[i * 3 + j] = E[i * 3 + 0] * E[0 * 3 + j] +
                               E[i * 3 + 1] * E[1 * 3 + j] +
                               E[i * 3 + 2] * E[2 * 3 + j];
#pragma unroll
        for (int i = 0; i < 9; ++i) E[i] = Q[i];
    }

#pragma unroll
    for (int i = 0; i < 9; ++i) E_out[k * 9 + i] = E[i];
}

// ---------------------------------------------------------------------------
// Kernel 2: out[t, n, i] = sum_j E_t[i][j] * x[n][j]
// Block = 256 threads, handles TILE_N rows of x for one t.
// x tile staged in LDS via float4; output written as aligned float4.
// Per-t output slab is N*3 = 1,500,000 floats (divisible by 4 -> 16B aligned).
// ---------------------------------------------------------------------------
#define TILE_N 1024

__global__ __launch_bounds__(256) void apply_kernel(const float* __restrict__ x,
                                                    const float* __restrict__ E_all,
                                                    float* __restrict__ out,
                                                    int N) {
    __shared__ __align__(16) float xs[TILE_N * 3];

    const int tid  = threadIdx.x;
    const int tile = blockIdx.x;
    const int tt   = blockIdx.y;

    const long n0   = (long)tile * TILE_N;
    const int  rows = min(TILE_N, (int)(N - n0));
    const int  nflt = rows * 3;
    const int  nvec = nflt >> 2;          // full float4 count
    const int  rem0 = nvec << 2;

    // E for this t -> registers (uniform broadcast)
    float E[9];
#pragma unroll
    for (int i = 0; i < 9; ++i) E[i] = E_all[tt * 9 + i];

    // stage x tile (coalesced float4; base offset n0*3 is /4 -> 16B aligned)
    const float* xsrc = x + n0 * 3;
    for (int v = tid; v < nvec; v += 256)
        reinterpret_cast<float4*>(xs)[v] =
            reinterpret_cast<const float4*>(xsrc)[v];
    for (int v = rem0 + tid; v < nflt; v += 256)
        xs[v] = xsrc[v];
    __syncthreads();

    float* dst = out + ((long)tt * N + n0) * 3;
    for (int v = tid; v < nvec; v += 256) {
        const int e0 = v << 2;
        float4 r;
        float* rp = &r.x;
#pragma unroll
        for (int c = 0; c < 4; ++c) {
            const int e = e0 + c;
            const int n = e / 3;          // magic-mul, small ints
            const int i = e - n * 3;
            rp[c] = E[i * 3 + 0] * xs[n * 3 + 0] +
                    E[i * 3 + 1] * xs[n * 3 + 1] +
                    E[i * 3 + 2] * xs[n * 3 + 2];
        }
        reinterpret_cast<float4*>(dst)[v] = r;
    }
    for (int v = rem0 + tid; v < nflt; v += 256) {
        const int n = v / 3;
        const int i = v - n * 3;
        dst[v] = E[i * 3 + 0] * xs[n * 3 + 0] +
                 E[i * 3 + 1] * xs[n * 3 + 1] +
                 E[i * 3 + 2] * xs[n * 3 + 2];
    }
}

extern "C" void kernel_launch(void* const* d_in, const int* in_sizes, int n_in,
                              void* d_out, int out_size, void* d_ws, size_t ws_size,
                              hipStream_t stream) {
    const float* x  = (const float*)d_in[0];   // (N, 3)
    const float* t  = (const float*)d_in[1];   // (T,)
    const float* M  = (const float*)d_in[2];   // (3, 3)
    const float* M0 = (const float*)d_in[3];   // (3, 3)
    // d_in[4] = b (3,) — never contributes: homogeneous coord of x_pad is 0.

    const int N = in_sizes[0] / 3;
    const int T = in_sizes[1];

    float* E_ws = (float*)d_ws;                 // T*9 floats
    float* out  = (float*)d_out;

    // 1) 64 tiny 3x3 expm's
    expm_kernel<<<(T + 63) / 64, 64, 0, stream>>>(t, M, M0, E_ws, T);

    // 2) apply: (T, N, 3) output
    dim3 grid((N + TILE_N - 1) / TILE_N, T);
    apply_kernel<<<grid, 256, 0, stream>>>(x, E_ws, out, N);
}